// Round 1
// baseline (160.867 us; speedup 1.0000x reference)
//
#include <hip/hip_runtime.h>

#define BATCH 4
#define NDIM 2048
#define MDIM 2048
#define CDIM 128

typedef short bf16x8 __attribute__((ext_vector_type(8)));   // 8 bf16 (4 VGPRs)
typedef float f32x4  __attribute__((ext_vector_type(4)));   // MFMA accumulator

// fp32 -> bf16 bits, round-to-nearest-even (inputs are finite normals).
__device__ __forceinline__ unsigned short f2bf(float f) {
    union { float f; unsigned int u; } v; v.f = f;
    unsigned int u = v.u;
    return (unsigned short)((u + 0x7FFFu + ((u >> 16) & 1u)) >> 16);
}

// Single fused kernel: 128x128 output tile per block; bf16 MFMA dots,
// fp32 row norms computed in-block during staging (no separate norm pass,
// no ws round-trip), fused epilogue.
// LDS = 64 KiB tiles (XOR-swizzled in 16B chunks so MFMA fragment reads are
// <=2-way) + 1 KiB norms. 2 blocks/CU.
__global__ __launch_bounds__(256) void sim_fused(
    const float* __restrict__ src, const float* __restrict__ tgt,
    float* __restrict__ out)
{
    __shared__ unsigned short As[128 * 128];   // src tile, bf16 bits
    __shared__ unsigned short Bs[128 * 128];   // tgt tile, bf16 bits
    __shared__ float ssq[128];                 // fp32 ||src_row||^2
    __shared__ float tsq[128];                 // fp32 ||tgt_row||^2

    const int tid  = threadIdx.x;
    const int lane = tid & 63;
    const int b    = blockIdx.z;
    const int i0   = blockIdx.y << 7;   // src-row base of tile
    const int j0   = blockIdx.x << 7;   // tgt-row base of tile

    const float4* s4 = (const float4*)(src + ((size_t)b * NDIM + i0) * CDIM);
    const float4* t4 = (const float4*)(tgt + ((size_t)b * MDIM + j0) * CDIM);

    // Stage 128x128 fp32 -> bf16 into LDS (4096 float4 per tensor, 16/thread)
    // and reduce fp32 row norms on the fly: the 32 consecutive lanes that
    // share `row` hold exactly that row's 32 float4s -> 5-step xor reduce.
    #pragma unroll 4
    for (int it = 0; it < 16; ++it) {
        int idx  = tid + it * 256;
        int row  = idx >> 5;           // 0..127, same for 32 consecutive tids
        int c4   = idx & 31;           // float4 chunk within row
        float4 va = s4[idx];
        float4 vb = t4[idx];

        float pa = va.x * va.x + va.y * va.y + va.z * va.z + va.w * va.w;
        float pb = vb.x * vb.x + vb.y * vb.y + vb.z * vb.z + vb.w * vb.w;
        #pragma unroll
        for (int off = 16; off >= 1; off >>= 1) {
            pa += __shfl_xor(pa, off, 64);   // stays within the 32-lane group
            pb += __shfl_xor(pb, off, 64);
        }
        if ((lane & 31) == 0) { ssq[row] = pa; tsq[row] = pb; }

        int chunk = c4 >> 1;           // 16B chunk (8 bf16)
        int half  = c4 & 1;
        int off2  = row * 128 + (((chunk ^ (row & 15)) << 3) + (half << 2));
        ushort4 ua, ub;
        ua.x = f2bf(va.x); ua.y = f2bf(va.y); ua.z = f2bf(va.z); ua.w = f2bf(va.w);
        ub.x = f2bf(vb.x); ub.y = f2bf(vb.y); ub.z = f2bf(vb.z); ub.w = f2bf(vb.w);
        *(ushort4*)&As[off2] = ua;
        *(ushort4*)&Bs[off2] = ub;
    }
    __syncthreads();

    const int wave = tid >> 6;
    const int wm   = (wave & 1) << 6;   // 64x64 quadrant per wave
    const int wn   = (wave >> 1) << 6;
    const int l16  = lane & 15;
    const int q    = lane >> 4;

    f32x4 acc[4][4];
    #pragma unroll
    for (int i = 0; i < 4; ++i)
        #pragma unroll
        for (int j = 0; j < 4; ++j) acc[i][j] = (f32x4){0.f, 0.f, 0.f, 0.f};

    // K = 128 in 4 MFMA steps of 32. A/B frag: lane holds row (wX+i*16+l16),
    // k = k0 + q*8 .. +7. Row%16 == l16, so swizzle = chunk ^ l16.
    #pragma unroll
    for (int k0 = 0; k0 < 4; ++k0) {
        int chunk = (k0 << 2) + q;     // (k0*32 + q*8) / 8
        int swz   = (chunk ^ l16) << 3;
        bf16x8 a[4], bv[4];
        #pragma unroll
        for (int i = 0; i < 4; ++i)
            a[i] = *(const bf16x8*)&As[(wm + (i << 4) + l16) * 128 + swz];
        #pragma unroll
        for (int j = 0; j < 4; ++j)
            bv[j] = *(const bf16x8*)&Bs[(wn + (j << 4) + l16) * 128 + swz];
        #pragma unroll
        for (int i = 0; i < 4; ++i)
            #pragma unroll
            for (int j = 0; j < 4; ++j)
                acc[i][j] = __builtin_amdgcn_mfma_f32_16x16x32_bf16(
                    a[i], bv[j], acc[i][j], 0, 0, 0);
    }

    // Epilogue. D layout: col(n) = lane&15, row(m) = q*4 + reg.
    float sq[4][4], isq[4][4];
    #pragma unroll
    for (int i = 0; i < 4; ++i) {
        float4 s4v = *(const float4*)&ssq[wm + (i << 4) + (q << 2)];
        sq[i][0] = s4v.x; sq[i][1] = s4v.y; sq[i][2] = s4v.z; sq[i][3] = s4v.w;
        #pragma unroll
        for (int r = 0; r < 4; ++r)
            isq[i][r] = __builtin_amdgcn_rsqf(fmaxf(sq[i][r], 1e-24f));
    }
    float tq[4], itq[4];
    #pragma unroll
    for (int j = 0; j < 4; ++j) {
        tq[j]  = tsq[wn + (j << 4) + l16];
        itq[j] = __builtin_amdgcn_rsqf(fmaxf(tq[j], 1e-24f));
    }

    float2* out2 = (float2*)out;
    #pragma unroll
    for (int i = 0; i < 4; ++i) {
        #pragma unroll
        for (int r = 0; r < 4; ++r) {
            int mrow = wm + (i << 4) + (q << 2) + r;          // src idx in tile
            size_t rowbase = ((size_t)b * NDIM + (size_t)(i0 + mrow)) * MDIM + j0;
            float sqr = sq[i][r], isr = isq[i][r];
            #pragma unroll
            for (int j = 0; j < 4; ++j) {
                int ncol = wn + (j << 4) + l16;               // tgt idx in tile
                float d   = acc[i][j][r];
                float cs  = d * isr * itq[j];
                float dsq = fmaf(-2.0f, d, sqr + tq[j]);
                float fd  = __builtin_amdgcn_sqrtf(fmaxf(dsq, 0.0f));
                float fdn = __builtin_amdgcn_rcpf(1.0f + fd);
                out2[rowbase + ncol] = make_float2(cs, fdn);
            }
        }
    }
}

extern "C" void kernel_launch(void* const* d_in, const int* in_sizes, int n_in,
                              void* d_out, int out_size, void* d_ws, size_t ws_size,
                              hipStream_t stream) {
    const float* src = (const float*)d_in[0];
    const float* tgt = (const float*)d_in[1];
    float* out = (float*)d_out;

    dim3 grid(MDIM / 128, NDIM / 128, BATCH);
    sim_fused<<<grid, dim3(256), 0, stream>>>(src, tgt, out);
}

// Round 2
// 147.686 us; speedup vs baseline: 1.0892x; 1.0892x over previous
//
#include <hip/hip_runtime.h>

#define BATCH 4
#define NDIM 2048
#define MDIM 2048
#define CDIM 128

typedef short bf16x8 __attribute__((ext_vector_type(8)));   // 8 bf16 (4 VGPRs)
typedef float f32x4  __attribute__((ext_vector_type(4)));   // MFMA accumulator

// fp32 -> bf16 bits, round-to-nearest-even (inputs are finite normals).
__device__ __forceinline__ unsigned short f2bf(float f) {
    union { float f; unsigned int u; } v; v.f = f;
    unsigned int u = v.u;
    return (unsigned short)((u + 0x7FFFu + ((u >> 16) & 1u)) >> 16);
}

// Kernel 1: per-row squared norms in fp32. One 32-lane group per row
// (float4 loads), 5-step xor reduce. ws[0..8191]=src rows, ws[8192..]=tgt.
__global__ __launch_bounds__(256) void norm_kernel(
    const float* __restrict__ src, const float* __restrict__ tgt,
    float* __restrict__ ws)
{
    int gid  = blockIdx.x * 256 + threadIdx.x;
    int wid  = gid >> 6;                   // 0..8191, two rows per wave
    int lane = gid & 63;
    int row  = (wid << 1) + (lane >> 5);   // 0..16383 virtual row
    const float* base = (row < BATCH * NDIM)
        ? (src + (size_t)row * CDIM)
        : (tgt + (size_t)(row - BATCH * NDIM) * CDIM);
    float4 v = ((const float4*)base)[lane & 31];
    float s = v.x * v.x + v.y * v.y + v.z * v.z + v.w * v.w;
    #pragma unroll
    for (int off = 16; off >= 1; off >>= 1) s += __shfl_xor(s, off, 64);
    if ((lane & 31) == 0) ws[row] = s;
}

// Kernel 2: 128x64 output tile per block (LDS 48 KiB -> 3 blocks/CU for
// phase stagger). bf16 MFMA dots; epilogue split by j-half so stores start
// after half the MFMAs and overlap the rest. XOR-swizzled LDS (16B chunk
// ^ (row&15)) keeps both staging writes and fragment reads conflict-free.
__global__ __launch_bounds__(256, 3) void sim_mfma(
    const float* __restrict__ src, const float* __restrict__ tgt,
    const float* __restrict__ ws, float* __restrict__ out)
{
    __shared__ unsigned short As[128 * 128];   // src tile, bf16 bits (32 KiB)
    __shared__ unsigned short Bs[64 * 128];    // tgt tile, bf16 bits (16 KiB)

    const int tid = threadIdx.x;
    const int b   = blockIdx.z;
    const int i0  = blockIdx.y << 7;   // src-row base of tile (128 rows)
    const int j0  = blockIdx.x << 6;   // tgt-row base of tile (64 rows)

    const float4* s4 = (const float4*)(src + ((size_t)b * NDIM + i0) * CDIM);
    const float4* t4 = (const float4*)(tgt + ((size_t)b * MDIM + j0) * CDIM);

    // Stage src 128x128 fp32 -> bf16 (4096 float4, 16/thread).
    #pragma unroll 4
    for (int it = 0; it < 16; ++it) {
        int idx  = tid + it * 256;
        int row  = idx >> 5;           // 0..127
        int c4   = idx & 31;           // float4 chunk within row
        float4 va = s4[idx];
        int chunk = c4 >> 1;           // 16B chunk (8 bf16)
        int half  = c4 & 1;
        int off   = row * 128 + (((chunk ^ (row & 15)) << 3) + (half << 2));
        ushort4 ua;
        ua.x = f2bf(va.x); ua.y = f2bf(va.y); ua.z = f2bf(va.z); ua.w = f2bf(va.w);
        *(ushort4*)&As[off] = ua;
    }
    // Stage tgt 64x128 fp32 -> bf16 (2048 float4, 8/thread).
    #pragma unroll 4
    for (int it = 0; it < 8; ++it) {
        int idx  = tid + it * 256;
        int row  = idx >> 5;           // 0..63
        int c4   = idx & 31;
        float4 vb = t4[idx];
        int chunk = c4 >> 1;
        int half  = c4 & 1;
        int off   = row * 128 + (((chunk ^ (row & 15)) << 3) + (half << 2));
        ushort4 ub;
        ub.x = f2bf(vb.x); ub.y = f2bf(vb.y); ub.z = f2bf(vb.z); ub.w = f2bf(vb.w);
        *(ushort4*)&Bs[off] = ub;
    }
    __syncthreads();

    const int wave = tid >> 6;
    const int lane = tid & 63;
    const int wm   = (wave & 1) << 6;   // 64-row half per wave
    const int wn   = (wave >> 1) << 5;  // 32-col half per wave
    const int l16  = lane & 15;
    const int q    = lane >> 4;

    // Norms (prefetch before compute; reads hit L2/L3).
    const float* nrmS = ws + (size_t)b * NDIM + i0;
    const float* nrmT = ws + (size_t)BATCH * NDIM + (size_t)b * MDIM + j0;

    float sq[4][4], isq[4][4];
    #pragma unroll
    for (int i = 0; i < 4; ++i) {
        float4 s4v = *(const float4*)&nrmS[wm + (i << 4) + (q << 2)];
        sq[i][0] = s4v.x; sq[i][1] = s4v.y; sq[i][2] = s4v.z; sq[i][3] = s4v.w;
        #pragma unroll
        for (int r = 0; r < 4; ++r)
            isq[i][r] = __builtin_amdgcn_rsqf(fmaxf(sq[i][r], 1e-24f));
    }
    float tq[2], itq[2];
    #pragma unroll
    for (int jh = 0; jh < 2; ++jh) {
        tq[jh]  = nrmT[wn + (jh << 4) + l16];
        itq[jh] = __builtin_amdgcn_rsqf(fmaxf(tq[jh], 1e-24f));
    }

    float2* out2 = (float2*)out;

    // Two j-half phases: full K-loop then immediate store, so the second
    // phase's MFMAs overlap the first phase's store drain.
    #pragma unroll
    for (int jh = 0; jh < 2; ++jh) {
        f32x4 acc[4];
        #pragma unroll
        for (int i = 0; i < 4; ++i) acc[i] = (f32x4){0.f, 0.f, 0.f, 0.f};

        const int brow = wn + (jh << 4) + l16;   // Bs row for this half
        #pragma unroll
        for (int k0 = 0; k0 < 4; ++k0) {
            int chunk = (k0 << 2) + q;           // (k0*32 + q*8) / 8
            int swz   = (chunk ^ l16) << 3;
            bf16x8 bv = *(const bf16x8*)&Bs[brow * 128 + swz];
            #pragma unroll
            for (int i = 0; i < 4; ++i) {
                bf16x8 a = *(const bf16x8*)&As[(wm + (i << 4) + l16) * 128 + swz];
                acc[i] = __builtin_amdgcn_mfma_f32_16x16x32_bf16(a, bv, acc[i], 0, 0, 0);
            }
        }

        // Store this j-half. D layout: col(n) = lane&15, row(m) = q*4 + reg.
        const int   ncol = wn + (jh << 4) + l16;
        const float tqj  = tq[jh], itj = itq[jh];
        #pragma unroll
        for (int i = 0; i < 4; ++i) {
            #pragma unroll
            for (int r = 0; r < 4; ++r) {
                int mrow = wm + (i << 4) + (q << 2) + r;      // src idx in tile
                size_t rowbase =
                    ((size_t)b * NDIM + (size_t)(i0 + mrow)) * MDIM + j0;
                float d   = acc[i][r];
                float cs  = d * isq[i][r] * itj;
                float dsq = fmaf(-2.0f, d, sq[i][r] + tqj);
                float fd  = __builtin_amdgcn_sqrtf(fmaxf(dsq, 0.0f));
                float fdn = __builtin_amdgcn_rcpf(1.0f + fd);
                out2[rowbase + ncol] = make_float2(cs, fdn);
            }
        }
    }
}

extern "C" void kernel_launch(void* const* d_in, const int* in_sizes, int n_in,
                              void* d_out, int out_size, void* d_ws, size_t ws_size,
                              hipStream_t stream) {
    const float* src = (const float*)d_in[0];
    const float* tgt = (const float*)d_in[1];
    float* ws  = (float*)d_ws;
    float* out = (float*)d_out;

    // 16384 rows, two rows per wave -> 2048 blocks of 256.
    norm_kernel<<<dim3(2048), dim3(256), 0, stream>>>(src, tgt, ws);

    dim3 grid(MDIM / 64, NDIM / 128, BATCH);
    sim_mfma<<<grid, dim3(256), 0, stream>>>(src, tgt, ws, out);
}

// Round 3
// 144.317 us; speedup vs baseline: 1.1147x; 1.0233x over previous
//
#include <hip/hip_runtime.h>

#define BATCH 4
#define NDIM 2048
#define MDIM 2048
#define CDIM 128
#define NROWS (BATCH * NDIM)   // 8192 rows per tensor

typedef short bf16x8 __attribute__((ext_vector_type(8)));   // 8 bf16 (4 VGPRs)
typedef float f32x4  __attribute__((ext_vector_type(4)));   // MFMA accumulator

// fp32 -> bf16 bits, round-to-nearest-even (inputs are finite normals).
__device__ __forceinline__ unsigned short f2bf(float f) {
    union { float f; unsigned int u; } v; v.f = f;
    unsigned int u = v.u;
    return (unsigned short)((u + 0x7FFFu + ((u >> 16) & 1u)) >> 16);
}

// 16B global->LDS DMA (no VGPR round-trip). LDS dest must be
// wave-uniform base + lane*16 -- our tid*16 layout satisfies this.
__device__ __forceinline__ void gload_lds16(const void* g, void* l) {
    __builtin_amdgcn_global_load_lds(
        (const __attribute__((address_space(1))) void*)g,
        (__attribute__((address_space(3))) void*)l, 16, 0, 0);
}

// Kernel 1 (prep): per-row fp32 norms AND one-time fp32->bf16 conversion,
// rows written PRE-SWIZZLED in 16B chunks (chunk ^ (row&15)) so sim can
// global_load_lds them linearly and read fragments with the XOR pattern.
// 32 lanes per row (one float4 each).
// ws layout: [0,2MB) src bf16 | [2MB,4MB) tgt bf16 | [4MB,+64KB) fp32 norms.
__global__ __launch_bounds__(256) void prep_kernel(
    const float* __restrict__ src, const float* __restrict__ tgt,
    unsigned short* __restrict__ bf, float* __restrict__ nrm)
{
    int gid = blockIdx.x * 256 + threadIdx.x;
    int row = gid >> 5;                 // 0..16383 (src then tgt)
    int l32 = gid & 31;
    const float* base = (row < NROWS)
        ? (src + (size_t)row * CDIM)
        : (tgt + (size_t)(row - NROWS) * CDIM);
    float4 v = ((const float4*)base)[l32];
    float s = v.x * v.x + v.y * v.y + v.z * v.z + v.w * v.w;
    #pragma unroll
    for (int off = 16; off >= 1; off >>= 1) s += __shfl_xor(s, off, 64);
    if (l32 == 0) nrm[row] = s;

    // swizzled bf16 store: chunk = 8 elems (16B); this lane owns half of one.
    int chunk = l32 >> 1;
    int half  = l32 & 1;
    unsigned short* dst = bf + (size_t)row * CDIM
                        + (((chunk ^ (row & 15)) << 3) + (half << 2));
    ushort4 u;
    u.x = f2bf(v.x); u.y = f2bf(v.y); u.z = f2bf(v.z); u.w = f2bf(v.w);
    *(ushort4*)dst = u;
}

// Kernel 2: 128x64 output tile (LDS 48 KiB bf16 -> 3 blocks/CU). Staging is
// pure global_load_lds DMA of the pre-converted, pre-swizzled bf16 rows:
// zero staging VALU. Compute/epilogue identical to previous round.
__global__ __launch_bounds__(256, 3) void sim_mfma(
    const unsigned short* __restrict__ bfS, const unsigned short* __restrict__ bfT,
    const float* __restrict__ nrm, float* __restrict__ out)
{
    __shared__ unsigned short As[128 * 128];   // src tile (32 KiB)
    __shared__ unsigned short Bs[64 * 128];    // tgt tile (16 KiB)

    const int tid = threadIdx.x;
    const int b   = blockIdx.z;
    const int i0  = blockIdx.y << 7;   // src-row base (128 rows)
    const int j0  = blockIdx.x << 6;   // tgt-row base (64 rows)

    const char* gA = (const char*)(bfS + ((size_t)b * NDIM + i0) * CDIM);
    const char* gB = (const char*)(bfT + ((size_t)b * MDIM + j0) * CDIM);
    char* lA = (char*)As;
    char* lB = (char*)Bs;
    const int t16 = tid << 4;

    // A: 32 KiB = 8 x (256 threads x 16B); B: 16 KiB = 4 x.
    #pragma unroll
    for (int it = 0; it < 8; ++it)
        gload_lds16(gA + t16 + it * 4096, lA + t16 + it * 4096);
    #pragma unroll
    for (int it = 0; it < 4; ++it)
        gload_lds16(gB + t16 + it * 4096, lB + t16 + it * 4096);
    __syncthreads();

    const int wave = tid >> 6;
    const int lane = tid & 63;
    const int wm   = (wave & 1) << 6;   // 64-row half per wave
    const int wn   = (wave >> 1) << 5;  // 32-col half per wave
    const int l16  = lane & 15;
    const int q    = lane >> 4;

    // Norms (L2-hot).
    const float* nrmS = nrm + (size_t)b * NDIM + i0;
    const float* nrmT = nrm + (size_t)NROWS + (size_t)b * MDIM + j0;

    float sq[4][4], isq[4][4];
    #pragma unroll
    for (int i = 0; i < 4; ++i) {
        float4 s4v = *(const float4*)&nrmS[wm + (i << 4) + (q << 2)];
        sq[i][0] = s4v.x; sq[i][1] = s4v.y; sq[i][2] = s4v.z; sq[i][3] = s4v.w;
        #pragma unroll
        for (int r = 0; r < 4; ++r)
            isq[i][r] = __builtin_amdgcn_rsqf(fmaxf(sq[i][r], 1e-24f));
    }
    float tq[2], itq[2];
    #pragma unroll
    for (int jh = 0; jh < 2; ++jh) {
        tq[jh]  = nrmT[wn + (jh << 4) + l16];
        itq[jh] = __builtin_amdgcn_rsqf(fmaxf(tq[jh], 1e-24f));
    }

    float2* out2 = (float2*)out;

    // Two j-half phases: full K-loop then immediate store.
    #pragma unroll
    for (int jh = 0; jh < 2; ++jh) {
        f32x4 acc[4];
        #pragma unroll
        for (int i = 0; i < 4; ++i) acc[i] = (f32x4){0.f, 0.f, 0.f, 0.f};

        const int brow = wn + (jh << 4) + l16;
        #pragma unroll
        for (int k0 = 0; k0 < 4; ++k0) {
            int chunk = (k0 << 2) + q;           // (k0*32 + q*8) / 8
            int swz   = (chunk ^ l16) << 3;      // row%16 == l16
            bf16x8 bv = *(const bf16x8*)&Bs[brow * 128 + swz];
            #pragma unroll
            for (int i = 0; i < 4; ++i) {
                bf16x8 a = *(const bf16x8*)&As[(wm + (i << 4) + l16) * 128 + swz];
                acc[i] = __builtin_amdgcn_mfma_f32_16x16x32_bf16(a, bv, acc[i], 0, 0, 0);
            }
        }

        // Store this j-half. D layout: col(n) = lane&15, row(m) = q*4 + reg.
        const int   ncol = wn + (jh << 4) + l16;
        const float tqj  = tq[jh], itj = itq[jh];
        #pragma unroll
        for (int i = 0; i < 4; ++i) {
            #pragma unroll
            for (int r = 0; r < 4; ++r) {
                int mrow = wm + (i << 4) + (q << 2) + r;
                size_t rowbase =
                    ((size_t)b * NDIM + (size_t)(i0 + mrow)) * MDIM + j0;
                float d   = acc[i][r];
                float cs  = d * isq[i][r] * itj;
                float dsq = fmaf(-2.0f, d, sq[i][r] + tqj);
                float fd  = __builtin_amdgcn_sqrtf(fmaxf(dsq, 0.0f));
                float fdn = __builtin_amdgcn_rcpf(1.0f + fd);
                out2[rowbase + ncol] = make_float2(cs, fdn);
            }
        }
    }
}

extern "C" void kernel_launch(void* const* d_in, const int* in_sizes, int n_in,
                              void* d_out, int out_size, void* d_ws, size_t ws_size,
                              hipStream_t stream) {
    const float* src = (const float*)d_in[0];
    const float* tgt = (const float*)d_in[1];
    float* out = (float*)d_out;

    unsigned short* bfS = (unsigned short*)d_ws;                 // 2 MiB
    unsigned short* bfT = bfS + (size_t)NROWS * CDIM;            // 2 MiB
    float*          nrm = (float*)(bfT + (size_t)NROWS * CDIM);  // 64 KiB

    // 16384 rows x 32 lanes = 524288 threads -> 2048 blocks.
    prep_kernel<<<dim3(2048), dim3(256), 0, stream>>>(src, tgt, bfS, nrm);

    dim3 grid(MDIM / 64, NDIM / 128, BATCH);
    sim_mfma<<<grid, dim3(256), 0, stream>>>(bfS, bfT, nrm, out);
}